// Round 8
// baseline (72.108 us; speedup 1.0000x reference)
//
#include <hip/hip_runtime.h>
#include <hip/hip_bf16.h>

// Causal conv1d as bf16 MFMA GEMM — r7 shell + fused in-kernel x transpose
// (B reg-staged from x f32 directly; xT workspace and transpose prep deleted).
// out[b,h,t] = sum_{c,k} x[b,c,t+k-3] * W[h, c*4+k] + bias[h]
// B=8, C=256, T=4096, H=512, K=4.

#define Bb 8
#define Cc 256
#define Tt 4096
#define Hh 512
#define Kk 4

typedef __attribute__((ext_vector_type(8))) short bf16x8;
typedef __attribute__((ext_vector_type(4))) float f32x4;

#define WS_NEEDED 1048576ULL   // Wt only: 4*512*256 bf16 = 1 MB

__device__ __forceinline__ void gload16(const void* g, void* l) {
    __builtin_amdgcn_global_load_lds(
        (const __attribute__((address_space(1))) void*)g,
        (__attribute__((address_space(3))) void*)l, 16, 0, 0);
}

// ---------- prep: W[h, c*4+k] f32 -> Wt[k][h][c] bf16 ----------
__global__ __launch_bounds__(256) void wt_prep_kernel(const float* __restrict__ W,
                                                      __hip_bfloat16* __restrict__ Wt) {
    int n = blockIdx.x * 256 + threadIdx.x;           // [0, 4*512*256)
    int c = n & 255;
    int h = (n >> 8) & 511;
    int k = n >> 17;
    Wt[n] = __float2bfloat16(W[h * (Cc * Kk) + c * Kk + k]);
}

// ---------- main: BM=256h x BN=128t, 4 waves (2Mx2N -> 128x64/wave), BK=32 ----------
// K-order: conv-k inner (kappa = s&3), ch-block outer (cs = (s>>2)*32); 32 steps.
// A: 3 bufs x [256 rows][4 slots x 16B] (gload_lds, swizzle in global src).
// B: 2 bufs x [192 rows][4 slots x 16B]; rows 0..130 written by reg-staged
//    fused transpose: 16 coalesced f32 loads -> cvt -> 2 swizzled ds_write_b128.
// Swizzle: slot_phys = slot_log ^ ((row>>1)&3) (validated r6/r7).
#define A_BUF   16384
#define B_BUF   12288
#define B_BASE  49152
#define LDS_TOTAL 73728

#define BAR __builtin_amdgcn_s_barrier()
#define LGKM0 do { asm volatile("s_waitcnt lgkmcnt(0)" ::: "memory"); \
                   __builtin_amdgcn_sched_barrier(0); } while (0)

// issue 16 (+16 tail) coalesced x loads for ch-block base csb -> vv/vvt
#define BLOADS(csb, vv, vvt) do {                                               \
    int tg_ = t0 - 3 + (tid >> 1);                                              \
    const float* xp_ = x + ((size_t)(b * Cc + (csb) + (tid & 1) * 16)) * Tt     \
                         + (tg_ >= 0 ? tg_ : 0);                                \
    _Pragma("unroll") for (int j = 0; j < 16; ++j) vv[j] = xp_[(size_t)j * Tt]; \
    if (tg_ < 0) { _Pragma("unroll") for (int j = 0; j < 16; ++j) vv[j] = 0.f; }\
    if (tid < 6) {                                                              \
        const float* xq_ = x + ((size_t)(b * Cc + (csb) + (tid & 1) * 16)) * Tt \
                             + (t0 - 3 + 128 + (tid >> 1));                     \
        _Pragma("unroll") for (int j = 0; j < 16; ++j) vvt[j] = xq_[(size_t)j * Tt]; \
    }                                                                           \
} while (0)

// cvt + swizzled ds_write of vv/vvt into B buffer dstbuf
#define BSTORE(dstbuf, vv, vvt) do {                                            \
    int r_ = tid >> 1, sw_ = (r_ >> 1) & 3, sl0_ = (tid & 1) * 2;               \
    short o_[16];                                                               \
    _Pragma("unroll") for (int j = 0; j < 16; ++j) {                            \
        __hip_bfloat16 h_ = __float2bfloat16(vv[j]);                            \
        o_[j] = *reinterpret_cast<short*>(&h_);                                 \
    }                                                                           \
    *(bf16x8*)((dstbuf) + r_ * 64 + (((sl0_    ) ^ sw_) << 4)) = *(bf16x8*)&o_[0]; \
    *(bf16x8*)((dstbuf) + r_ * 64 + (((sl0_ + 1) ^ sw_) << 4)) = *(bf16x8*)&o_[8]; \
    if (tid < 6) {                                                              \
        int r2_ = 128 + (tid >> 1), sw2_ = (r2_ >> 1) & 3;                      \
        short p_[16];                                                           \
        _Pragma("unroll") for (int j = 0; j < 16; ++j) {                        \
            __hip_bfloat16 h_ = __float2bfloat16(vvt[j]);                       \
            p_[j] = *reinterpret_cast<short*>(&h_);                             \
        }                                                                       \
        *(bf16x8*)((dstbuf) + r2_ * 64 + (((sl0_    ) ^ sw2_) << 4)) = *(bf16x8*)&p_[0]; \
        *(bf16x8*)((dstbuf) + r2_ * 64 + (((sl0_ + 1) ^ sw2_) << 4)) = *(bf16x8*)&p_[8]; \
    }                                                                           \
} while (0)

__global__ __launch_bounds__(256, 2) void conv_mfma_kernel(
    const float* __restrict__ x,
    const __hip_bfloat16* __restrict__ Wt,
    const float* __restrict__ bias,
    float* __restrict__ out)
{
    __shared__ __align__(1024) char smem[LDS_TOTAL];
    const int tid = threadIdx.x, lane = tid & 63, wave = tid >> 6;
    const int wr = wave >> 1, wc = wave & 1;          // 2(M h) x 2(N t)
    const int l15 = lane & 15, lg = lane >> 4;

    // XCD-bijective swizzle: 512 blocks, XCD x <-> batch x (4MB x-slice L2-resident)
    const int flat = blockIdx.x + 32 * blockIdx.y + 64 * blockIdx.z;
    const int swz  = (flat & 7) * 64 + (flat >> 3);
    const int t0 = (swz & 31) * 128;
    const int h0 = ((swz >> 5) & 1) * 256;
    const int b  = swz >> 6;

    const char* Wt_c = (const char*)Wt;

    // ---- A staging descriptors (linear LDS dst; swizzle folded into global src) ----
    const char* abase[4]; int adst_[4];
#pragma unroll
    for (int i = 0; i < 4; ++i) {
        int s = tid + i * 256;                        // 0..1023
        int row = s >> 2, sl = s & 3;
        int colch = (sl ^ ((row >> 1) & 3)) * 8;
        abase[i] = Wt_c + (((size_t)(h0 + row)) * Cc + colch) * 2;
        adst_[i] = s * 16;
    }

    // ---- fragment read offsets (r6/r7-validated swizzle) ----
    const int aoff0 = (wr * 128 + l15) * 64 + ((lg ^ ((l15 >> 1) & 3)) << 4);
    int btab[4];
#pragma unroll
    for (int k = 0; k < 4; ++k)
        btab[k] = (wc * 64 + l15 + k) * 64 + ((lg ^ (((l15 + k) >> 1) & 3)) << 4);

    char *A0 = smem, *A1 = smem + A_BUF, *A2 = smem + 2 * A_BUF;
    char *B0 = smem + B_BASE, *B1 = smem + B_BASE + B_BUF;

    // ---- prologue: B(cs=0) reg-loads, A(0), A(1); cvt+write B0; A(1) stays in flight ----
    {
        float pv[16], pvt[16];
        BLOADS(0, pv, pvt);
#pragma unroll
        for (int i = 0; i < 4; ++i) gload16(abase[i], A0 + adst_[i]);
#pragma unroll
        for (int i = 0; i < 4; ++i) gload16(abase[i] + 262144, A1 + adst_[i]);
        asm volatile("s_waitcnt vmcnt(8)" ::: "memory");   // all B-loads landed
        BSTORE(B0, pv, pvt);
        asm volatile("s_waitcnt vmcnt(4)" ::: "memory");   // A(0) landed
        asm volatile("s_waitcnt lgkmcnt(0)" ::: "memory"); // B0 writes visible
        BAR;
    }

    f32x4 acc[8][4] = {};

#pragma unroll 4
    for (int s = 0; s < 32; ++s) {
        const int kap = s & 3;
        const int bo  = (kap == 0) ? btab[0] : (kap == 1) ? btab[1]
                      : (kap == 2) ? btab[2] : btab[3];
        const bool doB = (kap == 0) && (s < 28);

        float bv_[16], bvt_[16];
        bf16x8 a_[4], bfr_[4];
        // -- P0: A fm0-3 + B frags; issue B reg-loads then A(s+2) gload_lds --
#pragma unroll
        for (int fm = 0; fm < 4; ++fm) a_[fm] = *(const bf16x8*)(A0 + aoff0 + fm * 1024);
#pragma unroll
        for (int ft = 0; ft < 4; ++ft) bfr_[ft] = *(const bf16x8*)(B0 + bo + ft * 1024);
        if (doB) BLOADS(((s >> 2) + 1) * 32, bv_, bvt_);
        if (s < 30) {
            const long au = (long)((s + 2) & 3) * 262144 + (long)((s + 2) >> 2) * 64;
#pragma unroll
            for (int i = 0; i < 4; ++i) gload16(abase[i] + au, A2 + adst_[i]);
        }
        BAR; LGKM0;
        __builtin_amdgcn_s_setprio(1);
#pragma unroll
        for (int fm = 0; fm < 4; ++fm)
#pragma unroll
            for (int ft = 0; ft < 4; ++ft)
                acc[fm][ft] = __builtin_amdgcn_mfma_f32_16x16x32_bf16(a_[fm], bfr_[ft], acc[fm][ft], 0, 0, 0);
        __builtin_amdgcn_s_setprio(0);
        BAR;
        // -- P1: A fm4-7 (reuses bfr_); cvt+write next B tile --
#pragma unroll
        for (int fm = 0; fm < 4; ++fm) a_[fm] = *(const bf16x8*)(A0 + aoff0 + (fm + 4) * 1024);
        if (doB) {
            asm volatile("s_waitcnt vmcnt(4)" ::: "memory");  // B reg-loads landed (A(s+2) in flight)
            BSTORE(B1, bv_, bvt_);
        }
        BAR; LGKM0;
        __builtin_amdgcn_s_setprio(1);
#pragma unroll
        for (int fm = 0; fm < 4; ++fm)
#pragma unroll
            for (int ft = 0; ft < 4; ++ft)
                acc[fm + 4][ft] = __builtin_amdgcn_mfma_f32_16x16x32_bf16(a_[fm], bfr_[ft], acc[fm + 4][ft], 0, 0, 0);
        __builtin_amdgcn_s_setprio(0);
        // counted vmcnt: keep this step's 4 A-gloads in flight, drain older
        if (s < 30)       asm volatile("s_waitcnt vmcnt(4)" ::: "memory");
        else if (s == 30) asm volatile("s_waitcnt vmcnt(0)" ::: "memory");
        BAR;
        // rotate buffers
        char* tp = A0; A0 = A1; A1 = A2; A2 = tp;
        if (kap == 3) { char* up = B0; B0 = B1; B1 = up; }
    }

    // ---- epilogue: D col=l15 -> t, row=lg*4+q -> h (r6/r7-validated) ----
#pragma unroll
    for (int fm = 0; fm < 8; ++fm) {
        int hb = h0 + wr * 128 + fm * 16 + lg * 4;
        float4 bs = *(const float4*)&bias[hb];
        const float* bsp = (const float*)&bs;
#pragma unroll
        for (int q = 0; q < 4; ++q)
#pragma unroll
            for (int ft = 0; ft < 4; ++ft) {
                int t = t0 + wc * 64 + ft * 16 + l15;
                out[((size_t)(b * Hh + hb + q)) * Tt + t] = acc[fm][ft][q] + bsp[q];
            }
    }
}

// ---------------- fallback (ws too small): fp32 kernel ----------------
#define TT 256
#define HT 8
#define CT 4
__global__ __launch_bounds__(256) void conv1d_f32_kernel(
    const float* __restrict__ x, const float* __restrict__ W,
    const float* __restrict__ bias, float* __restrict__ out)
{
    const int tid = threadIdx.x;
    const int t0 = blockIdx.x * TT;
    const int h0 = blockIdx.y * HT;
    const int b  = blockIdx.z;
    __shared__ float xs[CT][TT + Kk];
    float acc[HT];
#pragma unroll
    for (int h = 0; h < HT; ++h) acc[h] = 0.f;
    const float* xb = x + (size_t)b * Cc * Tt;
    for (int c0 = 0; c0 < Cc; c0 += CT) {
        __syncthreads();
#pragma unroll
        for (int cc = 0; cc < CT; ++cc)
            for (int j = tid; j < TT + Kk - 1; j += 256) {
                int idx = t0 - (Kk - 1) + j;
                xs[cc][j] = (idx >= 0) ? xb[(size_t)(c0 + cc) * Tt + idx] : 0.f;
            }
        __syncthreads();
#pragma unroll
        for (int cc = 0; cc < CT; ++cc) {
            float xv[Kk];
#pragma unroll
            for (int k = 0; k < Kk; ++k) xv[k] = xs[cc][tid + k];
#pragma unroll
            for (int h = 0; h < HT; ++h) {
                const float* wp = W + (size_t)(h0 + h) * (Cc * Kk) + (size_t)(c0 + cc) * Kk;
#pragma unroll
                for (int k = 0; k < Kk; ++k) acc[h] += wp[k] * xv[k];
            }
        }
    }
#pragma unroll
    for (int h = 0; h < HT; ++h)
        out[((size_t)b * Hh + (h0 + h)) * Tt + t0 + tid] = acc[h] + bias[h0 + h];
}

extern "C" void kernel_launch(void* const* d_in, const int* in_sizes, int n_in,
                              void* d_out, int out_size, void* d_ws, size_t ws_size,
                              hipStream_t stream) {
    const float* x    = (const float*)d_in[0];
    const float* W    = (const float*)d_in[1];
    const float* bias = (const float*)d_in[2];
    float* out        = (float*)d_out;

    if (ws_size >= WS_NEEDED) {
        __hip_bfloat16* Wt = (__hip_bfloat16*)d_ws;
        wt_prep_kernel<<<dim3((Kk * Hh * Cc) / 256), dim3(256), 0, stream>>>(W, Wt);
        conv_mfma_kernel<<<dim3(32, 2, 8), dim3(256), 0, stream>>>(x, Wt, bias, out);
    } else {
        conv1d_f32_kernel<<<dim3(Tt / TT, Hh / HT, Bb), dim3(256), 0, stream>>>(x, W, bias, out);
    }
}

// Round 9
// 49.329 us; speedup vs baseline: 1.4618x; 1.4618x over previous
//
#include <hip/hip_runtime.h>
#include <hip/hip_bf16.h>

// Causal conv1d as bf16 MFMA GEMM — r6 shell + frag-prefetch counted-lgkm
// pipeline + linear pre-tiled Wt2 staging.
// out[b,h,t] = sum_{c,k} x[b,c,t+k-3] * W[h, c*4+k] + bias[h]
// B=8, C=256, T=4096, H=512, K=4.

#define Bb 8
#define Cc 256
#define Tt 4096
#define Hh 512
#define Kk 4

typedef __attribute__((ext_vector_type(8))) short bf16x8;
typedef __attribute__((ext_vector_type(4))) float f32x4;

#define WS_XT_OFF   0
#define WS_WT_OFF   16777216
#define WS_ZERO_OFF 17825792
#define WS_NEEDED   17826816ULL

__device__ __forceinline__ void gload16(const void* g, void* l) {
    __builtin_amdgcn_global_load_lds(
        (const __attribute__((address_space(1))) void*)g,
        (__attribute__((address_space(3))) void*)l, 16, 0, 0);
}

// ---------- merged prep: xT transpose (blocks 0..2047) + Wt2 LDS-image pack ----------
// Wt2[h0t][st][slot][e]: slot s: row=(s>>2)&255, sl=s&3, kk=s>>10;
//   h = h0t*256+row, c = (st>>1)*32 + ((sl^((row>>1)&3))<<3)+e, k = (st&1)*2+kk.
__global__ __launch_bounds__(256) void prep_kernel(const float* __restrict__ x,
                                                   const float* __restrict__ W,
                                                   __hip_bfloat16* __restrict__ xT,
                                                   __hip_bfloat16* __restrict__ Wt2,
                                                   float* __restrict__ zeros) {
    __shared__ __hip_bfloat16 tile[64][72];
    const int bid = blockIdx.x;
    if (bid < 2048) {
        const int t0 = (bid & 63) * 64, c0 = ((bid >> 6) & 3) * 64, b = bid >> 8;
        const int lt = threadIdx.x & 63, lw = threadIdx.x >> 6;
#pragma unroll
        for (int i = 0; i < 16; ++i) {
            int cc = lw + i * 4;
            tile[cc][lt] = __float2bfloat16(x[((size_t)(b * Cc + c0 + cc)) * Tt + t0 + lt]);
        }
        __syncthreads();
#pragma unroll
        for (int i = 0; i < 2; ++i) {
            int tt = (threadIdx.x >> 3) + i * 32;
            int c8 = threadIdx.x & 7;
            short tmp[8];
#pragma unroll
            for (int j = 0; j < 8; ++j) {
                __hip_bfloat16 v = tile[c8 * 8 + j][tt];
                tmp[j] = *reinterpret_cast<short*>(&v);
            }
            *reinterpret_cast<bf16x8*>(&xT[((size_t)(b * Tt + t0 + tt)) * Cc + c0 + c8 * 8]) =
                *reinterpret_cast<bf16x8*>(tmp);
        }
    } else {
        int n2 = (bid - 2048) * 256 + threadIdx.x;    // [0, 524288)
        int e   = n2 & 7;
        int s   = (n2 >> 3) & 2047;
        int st  = (n2 >> 14) & 15;
        int h0t = n2 >> 18;
        int row = (s >> 2) & 255, sl = s & 3, kk = s >> 10;
        int c = (st >> 1) * 32 + ((sl ^ ((row >> 1) & 3)) << 3) + e;
        int k = (st & 1) * 2 + kk;
        int h = h0t * 256 + row;
        Wt2[n2] = __float2bfloat16(W[h * (Cc * Kk) + c * Kk + k]);
        if (bid == 2048) zeros[threadIdx.x] = 0.f;    // 1 KB zero page
    }
}

// ---------- main: BM=256h x BN=256t, 8 waves (2Mx4N -> 128x64/wave), 16x16x32 ----------
// K-step = 2 conv-k x 32 ch (GEMM-K 64); 16 steps; 4 phases/step with
// one-phase-ahead frag prefetch (counted lgkmcnt 4/8/4/0).
#define A_STRIDE 32768
#define B_BASE   98304
#define B_STRIDE 17408
#define LDS_TOTAL 133120

#define BAR __builtin_amdgcn_s_barrier()
#define LGKM(n) do { asm volatile("s_waitcnt lgkmcnt(" #n ")" ::: "memory"); \
                     __builtin_amdgcn_sched_barrier(0); } while (0)

__global__ __launch_bounds__(512, 1) void conv_mfma_kernel(
    const __hip_bfloat16* __restrict__ xT,
    const __hip_bfloat16* __restrict__ Wt2,
    const float* __restrict__ bias,
    const float* __restrict__ zeros,
    float* __restrict__ out)
{
    __shared__ __align__(1024) char smem[LDS_TOTAL];
    const int tid = threadIdx.x, lane = tid & 63, wave = tid >> 6;
    const int wr = wave >> 2, wc = wave & 3;          // 2(M h) x 4(N t)
    const int l15 = lane & 15, lg = lane >> 4;

    // XCD swizzle: 256 blocks, XCD x gets batch x (2MB xT slice L2-resident)
    const int nf = (blockIdx.x & 7) * 32 + (blockIdx.x >> 3);
    const int t0 = (nf & 15) * 256;
    const int h0 = ((nf >> 4) & 1) * 256;
    const int b  = nf >> 5;

    const char* aW   = (const char*)Wt2 + (h0 >> 8) * 524288;  // pre-tiled LDS image
    const char* xT_c = (const char*)xT;
    const char* zz   = (const char*)zeros;

    // ---- A staging: linear (slot i*512+tid), src = aW + step*32768 + slot*16 ----
    int aslot[4];
#pragma unroll
    for (int i = 0; i < 4; ++i) aslot[i] = (tid + i * 512) * 16;

    // ---- B staging descriptors (r6-validated) ----
    const char* bsrc[2]; int bdst[2];
#pragma unroll
    for (int i = 0; i < 2; ++i) {
        int s = tid + i * 512;                        // rows 0..255
        int row = s >> 2, sl = s & 3;
        int colch = (sl ^ ((row >> 1) & 3)) * 8;
        int tg = t0 - 3 + row;
        bsrc[i] = (tg >= 0 && tg < Tt)
                ? xT_c + (((size_t)b * Tt + tg) * Cc + colch) * 2 : zz;
        bdst[i] = s * 16;
    }
    const char* btsrc; {                              // tail rows 256..258 (+pad)
        int row = 256 + (lane >> 2), sl = lane & 3;
        int colch = (sl ^ ((row >> 1) & 3)) * 8;
        int tg = t0 - 3 + row;
        btsrc = (row <= 258 && tg < Tt)
              ? xT_c + (((size_t)b * Tt + tg) * Cc + colch) * 2 : zz;
    }

    // ---- fragment read offsets (r6-validated swizzle) ----
    const int aoffb = (wr * 128 + l15) * 64 + ((lg ^ ((l15 >> 1) & 3)) << 4);
    int bofftab[4];
#pragma unroll
    for (int k = 0; k < 4; ++k)
        bofftab[k] = (wc * 64 + l15 + k) * 64 + ((lg ^ (((l15 + k) >> 1) & 3)) << 4);
    const int boff0 = bofftab[0], boff1 = bofftab[1];
    const int boff2 = bofftab[2], boff3 = bofftab[3];

    f32x4 acc[8][4] = {};

    // ---- prologue: A(0), B(0), A(1); vmcnt(4) keeps A(1) in flight ----
#pragma unroll
    for (int i = 0; i < 4; ++i) gload16(aW + aslot[i], smem + aslot[i]);
#pragma unroll
    for (int i = 0; i < 2; ++i) gload16(bsrc[i], smem + B_BASE + bdst[i]);
    gload16(btsrc, smem + B_BASE + 16384);
#pragma unroll
    for (int i = 0; i < 4; ++i) gload16(aW + 32768 + aslot[i], smem + A_STRIDE + aslot[i]);
    asm volatile("s_waitcnt vmcnt(4)" ::: "memory");
    BAR;

    // ---- main loop: 16 K-steps x 4 phases, frag prefetch 1 phase ahead ----
#pragma unroll
    for (int s = 0; s < 16; ++s) {
        const char* Ab  = smem + (s % 3) * A_STRIDE;
        const char* Bbf = smem + B_BASE + ((s >> 1) & 1) * B_STRIDE;
        char* And = smem + ((s + 2) % 3) * A_STRIDE;
        char* Bnd = smem + B_BASE + (((s >> 1) + 1) & 1) * B_STRIDE;
        const bool doA = (s + 2) <= 15;
        const bool doB = ((s & 1) == 0) && ((s >> 1) + 1 <= 7);
        const long aoffg = (long)(s + 2) * 32768;
        const int  badv  = ((s >> 1) + 1) * 64;
        const int  bo0 = (s & 1) ? boff2 : boff0;
        const int  bo1 = (s & 1) ? boff3 : boff1;

        bf16x8 fA0[4], fB0[4], fA1[4], fA2[4], fB2[4], fA3[4];

        // -- P0: read F0(8) + F1(4); stage A half1; lgkm(4) -> F0 ready --
#pragma unroll
        for (int fm = 0; fm < 4; ++fm) fA0[fm] = *(const bf16x8*)(Ab + aoffb + fm * 1024);
#pragma unroll
        for (int ft = 0; ft < 4; ++ft) fB0[ft] = *(const bf16x8*)(Bbf + bo0 + ft * 1024);
#pragma unroll
        for (int fm = 0; fm < 4; ++fm) fA1[fm] = *(const bf16x8*)(Ab + aoffb + (fm + 4) * 1024);
        if (doA) { gload16(aW + aoffg + aslot[0], And + aslot[0]);
                   gload16(aW + aoffg + aslot[1], And + aslot[1]); }
        BAR; LGKM(4);
        __builtin_amdgcn_s_setprio(1);
#pragma unroll
        for (int fm = 0; fm < 4; ++fm)
#pragma unroll
            for (int ft = 0; ft < 4; ++ft)
                acc[fm][ft] = __builtin_amdgcn_mfma_f32_16x16x32_bf16(fA0[fm], fB0[ft], acc[fm][ft], 0, 0, 0);
        __builtin_amdgcn_s_setprio(0);
        BAR;

        // -- P1: read F2(8); stage A half2; lgkm(8) -> F1 ready --
#pragma unroll
        for (int fm = 0; fm < 4; ++fm) fA2[fm] = *(const bf16x8*)(Ab + 16384 + aoffb + fm * 1024);
#pragma unroll
        for (int ft = 0; ft < 4; ++ft) fB2[ft] = *(const bf16x8*)(Bbf + bo1 + ft * 1024);
        if (doA) { gload16(aW + aoffg + aslot[2], And + aslot[2]);
                   gload16(aW + aoffg + aslot[3], And + aslot[3]); }
        BAR; LGKM(8);
        __builtin_amdgcn_s_setprio(1);
#pragma unroll
        for (int fm = 0; fm < 4; ++fm)
#pragma unroll
            for (int ft = 0; ft < 4; ++ft)
                acc[fm + 4][ft] = __builtin_amdgcn_mfma_f32_16x16x32_bf16(fA1[fm], fB0[ft], acc[fm + 4][ft], 0, 0, 0);
        __builtin_amdgcn_s_setprio(0);
        BAR;

        // -- P2: read F3(4); stage B; lgkm(4) -> F2 ready --
#pragma unroll
        for (int fm = 0; fm < 4; ++fm) fA3[fm] = *(const bf16x8*)(Ab + 16384 + aoffb + (fm + 4) * 1024);
        if (doB) { gload16(bsrc[0] + badv, Bnd + bdst[0]);
                   gload16(bsrc[1] + badv, Bnd + bdst[1]); }
        BAR; LGKM(4);
        __builtin_amdgcn_s_setprio(1);
#pragma unroll
        for (int fm = 0; fm < 4; ++fm)
#pragma unroll
            for (int ft = 0; ft < 4; ++ft)
                acc[fm][ft] = __builtin_amdgcn_mfma_f32_16x16x32_bf16(fA2[fm], fB2[ft], acc[fm][ft], 0, 0, 0);
        __builtin_amdgcn_s_setprio(0);
        BAR;

        // -- P3: stage B tail; counted vmcnt; lgkm(0) -> F3 ready --
        if (doB) gload16(btsrc + badv, Bnd + 16384);
        if (s < 14) {
            if ((s & 1) == 0) asm volatile("s_waitcnt vmcnt(7)" ::: "memory");
            else              asm volatile("s_waitcnt vmcnt(4)" ::: "memory");
        } else if (s == 14)   asm volatile("s_waitcnt vmcnt(0)" ::: "memory");
        BAR; LGKM(0);
        __builtin_amdgcn_s_setprio(1);
#pragma unroll
        for (int fm = 0; fm < 4; ++fm)
#pragma unroll
            for (int ft = 0; ft < 4; ++ft)
                acc[fm + 4][ft] = __builtin_amdgcn_mfma_f32_16x16x32_bf16(fA3[fm], fB2[ft], acc[fm + 4][ft], 0, 0, 0);
        __builtin_amdgcn_s_setprio(0);
        BAR;
    }

    // ---- epilogue: D col=l15 -> t, row=lg*4+q -> h (r6-validated) ----
#pragma unroll
    for (int fm = 0; fm < 8; ++fm) {
        int hb = h0 + wr * 128 + fm * 16 + lg * 4;
        float4 bs = *(const float4*)&bias[hb];
        const float* bsp = (const float*)&bs;
#pragma unroll
        for (int q = 0; q < 4; ++q)
#pragma unroll
            for (int ft = 0; ft < 4; ++ft) {
                int t = t0 + wc * 64 + ft * 16 + l15;
                out[((size_t)(b * Hh + hb + q)) * Tt + t] = acc[fm][ft][q] + bsp[q];
            }
    }
}

// ---------------- fallback (ws too small): fp32 kernel ----------------
#define TT 256
#define HT 8
#define CT 4
__global__ __launch_bounds__(256) void conv1d_f32_kernel(
    const float* __restrict__ x, const float* __restrict__ W,
    const float* __restrict__ bias, float* __restrict__ out)
{
    const int tid = threadIdx.x;
    const int t0 = blockIdx.x * TT;
    const int h0 = blockIdx.y * HT;
    const int b  = blockIdx.z;
    __shared__ float xs[CT][TT + Kk];
    float acc[HT];
#pragma unroll
    for (int h = 0; h < HT; ++h) acc[h] = 0.f;
    const float* xb = x + (size_t)b * Cc * Tt;
    for (int c0 = 0; c0 < Cc; c0 += CT) {
        __syncthreads();
#pragma unroll
        for (int cc = 0; cc < CT; ++cc)
            for (int j = tid; j < TT + Kk - 1; j += 256) {
                int idx = t0 - (Kk - 1) + j;
                xs[cc][j] = (idx >= 0) ? xb[(size_t)(c0 + cc) * Tt + idx] : 0.f;
            }
        __syncthreads();
#pragma unroll
        for (int cc = 0; cc < CT; ++cc) {
            float xv[Kk];
#pragma unroll
            for (int k = 0; k < Kk; ++k) xv[k] = xs[cc][tid + k];
#pragma unroll
            for (int h = 0; h < HT; ++h) {
                const float* wp = W + (size_t)(h0 + h) * (Cc * Kk) + (size_t)(c0 + cc) * Kk;
#pragma unroll
                for (int k = 0; k < Kk; ++k) acc[h] += wp[k] * xv[k];
            }
        }
    }
#pragma unroll
    for (int h = 0; h < HT; ++h)
        out[((size_t)b * Hh + (h0 + h)) * Tt + t0 + tid] = acc[h] + bias[h0 + h];
}

extern "C" void kernel_launch(void* const* d_in, const int* in_sizes, int n_in,
                              void* d_out, int out_size, void* d_ws, size_t ws_size,
                              hipStream_t stream) {
    const float* x    = (const float*)d_in[0];
    const float* W    = (const float*)d_in[1];
    const float* bias = (const float*)d_in[2];
    float* out        = (float*)d_out;

    if (ws_size >= WS_NEEDED) {
        __hip_bfloat16* xT  = (__hip_bfloat16*)((char*)d_ws + WS_XT_OFF);
        __hip_bfloat16* Wt2 = (__hip_bfloat16*)((char*)d_ws + WS_WT_OFF);
        float* zeros        = (float*)((char*)d_ws + WS_ZERO_OFF);

        prep_kernel<<<dim3(4096), dim3(256), 0, stream>>>(x, W, xT, Wt2, zeros);
        conv_mfma_kernel<<<dim3(256), dim3(512), 0, stream>>>(xT, Wt2, bias, zeros, out);
    } else {
        conv1d_f32_kernel<<<dim3(Tt / TT, Hh / HT, Bb), dim3(256), 0, stream>>>(x, W, bias, out);
    }
}